// Round 1
// baseline (86.827 us; speedup 1.0000x reference)
//
#include <hip/hip_runtime.h>
#include <cfloat>

// Problem constants (from reference): B,C,L,N,S
constexpr int Cc = 256;
constexpr int Lc = 512;
constexpr int Nc = 1024;
constexpr int Sc = 8;

// One thread per output element (n, c, j).
// C*S = 2048 = 8 blocks of 256 threads per ROI -> n is block-uniform,
// so rois/roi_idx loads are scalar (wave-uniform).
__global__ __launch_bounds__(256) void roi_pool_kernel(
    const float* __restrict__ sentences,   // (B, C, L)
    const int*   __restrict__ rois,        // (N, 2)
    const int*   __restrict__ roi_idx,     // (N,)
    float*       __restrict__ out)         // (N, C, S)
{
    const int blk  = blockIdx.x;                 // 0 .. N*8-1
    const int n    = blk >> 3;                   // 8 blocks per ROI
    const int base = ((blk & 7) << 8) | threadIdx.x;  // 0 .. 2047 within ROI
    const int c    = base >> 3;
    const int j    = base & 7;

    const int x1 = rois[2 * n];
    const int x2 = rois[2 * n + 1];
    const int lr = x2 - x1;
    const int b  = roi_idx[n];

    // start = x1 + (j*lr)//S ; end = x1 + ceil((j+1)*lr / S)
    const int start = x1 + ((j * lr) >> 3);
    const int end   = x1 + (((j + 1) * lr + Sc - 1) >> 3);

    const float* row = sentences + ((size_t)b * Cc + c) * Lc;

    float m = -FLT_MAX;
    for (int p = start; p < end; ++p) {
        m = fmaxf(m, row[p]);
    }

    out[(size_t)n * (Cc * Sc) + base] = m;
}

extern "C" void kernel_launch(void* const* d_in, const int* in_sizes, int n_in,
                              void* d_out, int out_size, void* d_ws, size_t ws_size,
                              hipStream_t stream) {
    const float* sentences = (const float*)d_in[0];
    const int*   rois      = (const int*)d_in[1];
    const int*   roi_idx   = (const int*)d_in[2];
    float*       out       = (float*)d_out;

    const int total  = Nc * Cc * Sc;          // 2,097,152
    const int block  = 256;
    const int grid   = total / block;         // 8192

    roi_pool_kernel<<<grid, block, 0, stream>>>(sentences, rois, roi_idx, out);
}